// Round 7
// baseline (386.951 us; speedup 1.0000x reference)
//
#include <hip/hip_runtime.h>
#include <math.h>

#define NN 65536
#define EE 1048576
#define ET (EE + NN)

#define CAPB 5120          // staging capacity per coarse bucket (mean 4352, +11.6 sigma)
#define EPB 4096           // edges per pass-1 block
#define P1B (ET / EPB)     // 272 blocks

// ---------------- CSR build via 2-pass coarse-bucket counting sort ----------------
__global__ __launch_bounds__(256) void bucket_pass1(const int* __restrict__ ei,
                                                    unsigned* __restrict__ staging,
                                                    unsigned* __restrict__ staging2,
                                                    int* __restrict__ gcnt) {
  __shared__ int hist[256];
  __shared__ int lbase[256];
  int t = threadIdx.x;
  hist[t] = 0;
  __syncthreads();
  int base = blockIdx.x * EPB;
  unsigned pk[16];
  int bk[16];
  #pragma unroll
  for (int j = 0; j < 16; ++j) {
    int e = base + j * 256 + t;
    int s, d;
    if (e < EE) { s = ei[e]; d = ei[EE + e]; } else { s = d = e - EE; }
    pk[j] = ((unsigned)s << 8) | (unsigned)(d & 255);
    bk[j] = d >> 8;
    atomicAdd(&hist[bk[j]], 1);
  }
  __syncthreads();
  lbase[t] = atomicAdd(&gcnt[t], hist[t]);   // reserve contiguous chunk per bucket
  __syncthreads();
  #pragma unroll
  for (int j = 0; j < 16; ++j) {
    int e = base + j * 256 + t;
    int pos = atomicAdd(&lbase[bk[j]], 1);
    staging[(size_t)bk[j] * CAPB + pos] = pk[j];
    staging2[(size_t)bk[j] * CAPB + pos] = (unsigned)e;
  }
}

__global__ __launch_bounds__(256) void bucket_pass2(const unsigned* __restrict__ staging,
                                                    const unsigned* __restrict__ staging2,
                                                    const int* __restrict__ gcnt,
                                                    int* __restrict__ row_ptr,
                                                    unsigned short* __restrict__ col,
                                                    unsigned short* __restrict__ dste,
                                                    int* __restrict__ orig) {
  __shared__ int pref[256];
  __shared__ int hist[256];
  __shared__ int loc[256];
  __shared__ int cnt2[256];
  __shared__ unsigned lin[CAPB];
  __shared__ unsigned lout[CAPB];
  __shared__ int lorig[CAPB];
  int t = threadIdx.x, b = blockIdx.x;

  pref[t] = gcnt[t];
  hist[t] = 0;
  __syncthreads();
  for (int off = 1; off < 256; off <<= 1) {      // inclusive scan of bucket counts
    int v = (t >= off) ? pref[t - off] : 0;
    __syncthreads();
    pref[t] += v;
    __syncthreads();
  }
  int rowbase = (b > 0) ? pref[b - 1] : 0;
  int nb = gcnt[b];

  for (int i = t; i < nb; i += 256) {
    unsigned v = staging[(size_t)b * CAPB + i];
    lin[i] = v;
    atomicAdd(&hist[v & 255], 1);
  }
  __syncthreads();
  loc[t] = hist[t];
  __syncthreads();
  for (int off = 1; off < 256; off <<= 1) {      // inclusive scan of local hist
    int v = (t >= off) ? loc[t - off] : 0;
    __syncthreads();
    loc[t] += v;
    __syncthreads();
  }
  int excl = loc[t] - hist[t];
  row_ptr[b * 256 + t] = rowbase + excl;
  cnt2[t] = excl;
  if (b == 255 && t == 255) row_ptr[NN] = rowbase + nb;
  __syncthreads();
  for (int i = t; i < nb; i += 256) {
    unsigned v = lin[i];
    int r = atomicAdd(&cnt2[v & 255], 1);
    lout[r] = v;
    lorig[r] = (int)staging2[(size_t)b * CAPB + i];
  }
  __syncthreads();
  for (int i = t; i < nb; i += 256) {            // coalesced final writes
    unsigned v = lout[i];
    col[rowbase + i] = (unsigned short)(v >> 8);
    dste[rowbase + i] = (unsigned short)(b * 256 + (v & 255));
    orig[rowbase + i] = lorig[i];
  }
}

// -------- dense: h = x@W, al_s/al_d, residual; register-blocked over nodes --------
// hW is written as bf16 (RNE) for the gather; al uses full f32 h.
template<int DIN, int DOUT, int H, bool HAS_RES, int NPW>
__global__ __launch_bounds__(256) void gemm_al_kernel(
    const float* __restrict__ xin, const float* __restrict__ W,
    const float* __restrict__ asrc, const float* __restrict__ adst,
    const float* __restrict__ Aw, const float* __restrict__ Ab,
    unsigned short* __restrict__ hw16, float* __restrict__ res,
    float* __restrict__ als, float* __restrict__ ald)
{
  constexpr int GPW = 64 / DOUT;
  constexpr int NPB = 4 * NPW * GPW;   // nodes per block (4 waves)
  constexpr int DINP = DIN + 4;        // padded LDS stride
  __shared__ float xs[NPB][DINP];

  int wave = threadIdx.x >> 6;
  int lane = threadIdx.x & 63;
  int l = lane % DOUT;
  int sub = lane / DOUT;
  int block_base = blockIdx.x * NPB;

  {
    constexpr int NV = NPB * DIN / 4;
    const float4* xin4 = (const float4*)(xin + (size_t)block_base * DIN);
    for (int i = threadIdx.x; i < NV; i += 256) {
      float4 v = xin4[i];
      int flat = i * 4;
      int nd = flat / DIN, k = flat % DIN;
      *(float4*)&xs[nd][k] = v;
    }
  }
  __syncthreads();

  int nl = wave * (NPW * GPW) + sub * NPW;
  float acc[NPW], racc[NPW];
  #pragma unroll
  for (int n = 0; n < NPW; ++n) { acc[n] = 0.f; racc[n] = 0.f; }

  for (int k = 0; k < DIN; k += 4) {
    float w0 = W[(k + 0) * DOUT + l];
    float w1 = W[(k + 1) * DOUT + l];
    float w2 = W[(k + 2) * DOUT + l];
    float w3 = W[(k + 3) * DOUT + l];
    float a0 = 0.f, a1 = 0.f, a2 = 0.f, a3 = 0.f;
    if (HAS_RES) {
      a0 = Aw[(k + 0) * DOUT + l];
      a1 = Aw[(k + 1) * DOUT + l];
      a2 = Aw[(k + 2) * DOUT + l];
      a3 = Aw[(k + 3) * DOUT + l];
    }
    #pragma unroll
    for (int n = 0; n < NPW; ++n) {
      float4 xv = *(const float4*)&xs[nl + n][k];
      acc[n] = fmaf(xv.x, w0, fmaf(xv.y, w1, fmaf(xv.z, w2, fmaf(xv.w, w3, acc[n]))));
      if (HAS_RES)
        racc[n] = fmaf(xv.x, a0, fmaf(xv.y, a1, fmaf(xv.z, a2, fmaf(xv.w, a3, racc[n]))));
    }
  }

  int head = l >> 2, c = l & 3;
  float sa = asrc[l];
  float da = adst[l];
  #pragma unroll
  for (int n = 0; n < NPW; ++n) {
    size_t node = (size_t)(block_base + nl + n);
    float hh = acc[n];
    unsigned u = __float_as_uint(hh);
    hw16[node * DOUT + l] = (unsigned short)((u + 0x7fffu + ((u >> 16) & 1u)) >> 16);
    if (HAS_RES) res[node * DOUT + l] = racc[n] + Ab[l];
    float ps = hh * sa, pd = hh * da;
    ps += __shfl_xor(ps, 1); ps += __shfl_xor(ps, 2);
    pd += __shfl_xor(pd, 1); pd += __shfl_xor(pd, 2);
    if (c == 0) {
      als[node * H + head] = ps;
      ald[node * H + head] = pd;
    }
  }
}

// ---------------- fused gather: bf16x2 channels, DOUT/2 lanes per node ----------------
template<int DOUT, int H, bool HAS_RES>
__global__ __launch_bounds__(256) void gat_gather_kernel(
    const int* __restrict__ row_ptr, const unsigned short* __restrict__ col,
    const float* __restrict__ als, const float* __restrict__ ald,
    const unsigned* __restrict__ hw2,   // bf16x2: channels (2l, 2l+1)
    const float* __restrict__ bias, const float* __restrict__ g,
    const float* __restrict__ be, const float* __restrict__ res,
    float* __restrict__ out, float* __restrict__ inv_s_out)
{
  constexpr int G = DOUT / 2;          // lanes per node
  int tid = blockIdx.x * 256 + threadIdx.x;
  int node = tid / G;
  int l = threadIdx.x % G;             // group lane: channels 2l, 2l+1
  int h = l >> 1;                      // head (2 lanes per head)

  int r0 = row_ptr[node], r1 = row_ptr[node + 1];
  float ald_h = ald[node * H + h];

  float acc0 = 0.f, acc1 = 0.f, ss = 0.f;
  int e = r0;
  for (; e + 3 < r1; e += 4) {
    int s0 = col[e], s1 = col[e + 1], s2 = col[e + 2], s3 = col[e + 3];
    float av0 = als[s0 * H + h];
    float av1 = als[s1 * H + h];
    float av2 = als[s2 * H + h];
    float av3 = als[s3 * H + h];
    unsigned p0 = hw2[s0 * G + l];
    unsigned p1 = hw2[s1 * G + l];
    unsigned p2 = hw2[s2 * G + l];
    unsigned p3 = hw2[s3 * G + l];
    float lg0 = av0 + ald_h; lg0 = lg0 > 0.f ? lg0 : 0.2f * lg0;
    float lg1 = av1 + ald_h; lg1 = lg1 > 0.f ? lg1 : 0.2f * lg1;
    float lg2 = av2 + ald_h; lg2 = lg2 > 0.f ? lg2 : 0.2f * lg2;
    float lg3 = av3 + ald_h; lg3 = lg3 > 0.f ? lg3 : 0.2f * lg3;
    float e0 = __expf(lg0), e1 = __expf(lg1), e2 = __expf(lg2), e3 = __expf(lg3);
    ss += (e0 + e1) + (e2 + e3);
    acc0 += e0 * __uint_as_float(p0 << 16) + e1 * __uint_as_float(p1 << 16)
          + e2 * __uint_as_float(p2 << 16) + e3 * __uint_as_float(p3 << 16);
    acc1 += e0 * __uint_as_float(p0 & 0xffff0000u) + e1 * __uint_as_float(p1 & 0xffff0000u)
          + e2 * __uint_as_float(p2 & 0xffff0000u) + e3 * __uint_as_float(p3 & 0xffff0000u);
  }
  for (; e < r1; ++e) {
    int s0 = col[e];
    float av0 = als[s0 * H + h];
    unsigned p0 = hw2[s0 * G + l];
    float lg0 = av0 + ald_h; lg0 = lg0 > 0.f ? lg0 : 0.2f * lg0;
    float e0 = __expf(lg0);
    ss += e0;
    acc0 += e0 * __uint_as_float(p0 << 16);
    acc1 += e0 * __uint_as_float(p0 & 0xffff0000u);
  }

  float inv = 1.f / ss;                // identical across the 2 lanes of a head
  if ((l & 1) == 0) inv_s_out[node * H + h] = inv;

  // epilogue: normalize -> bias -> elu -> layernorm -> (+res), 2 channels/lane
  float2 bb = ((const float2*)bias)[l];
  float v0 = acc0 * inv + bb.x;
  float v1 = acc1 * inv + bb.y;
  v0 = v0 > 0.f ? v0 : expm1f(v0);
  v1 = v1 > 0.f ? v1 : expm1f(v1);
  float sum = v0 + v1;
  #pragma unroll
  for (int o = G / 2; o; o >>= 1) sum += __shfl_xor(sum, o);
  float mu = sum * (1.f / DOUT);
  float d0 = v0 - mu, d1 = v1 - mu;
  float vs = d0 * d0 + d1 * d1;
  #pragma unroll
  for (int o = G / 2; o; o >>= 1) vs += __shfl_xor(vs, o);
  float rstd = rsqrtf(vs * (1.f / DOUT) + 1e-5f);
  float2 gg = ((const float2*)g)[l];
  float2 ee = ((const float2*)be)[l];
  float y0 = d0 * rstd * gg.x + ee.x;
  float y1 = d1 * rstd * gg.y + ee.y;
  if (HAS_RES) {
    float2 rr = ((const float2*)res)[node * G + l];
    y0 += rr.x; y1 += rr.y;
  }
  ((float2*)out)[node * G + l] = make_float2(y0, y1);
}

// ------- per-edge head-mean alpha in CSR order (dst rows L1-hot) + fused exp-sum -------
template<int H>
__global__ __launch_bounds__(256) void amean_csr_kernel(
    const unsigned short* __restrict__ col, const unsigned short* __restrict__ dste,
    const int* __restrict__ orig,
    const float* __restrict__ als, const float* __restrict__ ald,
    const float* __restrict__ inv_s,
    float* __restrict__ amean, float* __restrict__ ssum_out)
{
  __shared__ float red[4];
  int i = blockIdx.x * 256 + threadIdx.x;
  float ex = 0.f;
  if (i < ET) {
    int s = col[i], d = dste[i];
    int oe = orig[i];
    const float4* as4 = (const float4*)(als + (size_t)s * H);
    const float4* ad4 = (const float4*)(ald + (size_t)d * H);
    const float4* iv4 = (const float4*)(inv_s + (size_t)d * H);
    float t = 0.f;
    #pragma unroll
    for (int q = 0; q < H / 4; ++q) {
      float4 a = as4[q], b = ad4[q], c = iv4[q];
      float l0 = a.x + b.x; l0 = l0 > 0.f ? l0 : 0.2f * l0;
      float l1 = a.y + b.y; l1 = l1 > 0.f ? l1 : 0.2f * l1;
      float l2 = a.z + b.z; l2 = l2 > 0.f ? l2 : 0.2f * l2;
      float l3 = a.w + b.w; l3 = l3 > 0.f ? l3 : 0.2f * l3;
      t += __expf(l0) * c.x + __expf(l1) * c.y + __expf(l2) * c.z + __expf(l3) * c.w;
    }
    t *= (1.f / H);
    if (oe < EE) {          // skip self-loop slots
      amean[oe] = t;        // 4B scatter (fire-and-forget)
      ex = __expf(t);
    }
  }
  #pragma unroll
  for (int o = 32; o; o >>= 1) ex += __shfl_xor(ex, o);
  if ((threadIdx.x & 63) == 0) red[threadIdx.x >> 6] = ex;
  __syncthreads();
  if (threadIdx.x == 0)
    atomicAdd(ssum_out, (red[0] + red[1]) + (red[2] + red[3]));
}

__global__ __launch_bounds__(256) void write_softmax_kernel(
    const float* __restrict__ a, int n, const float* __restrict__ ssum,
    float* __restrict__ out)
{
  float inv = 1.f / *ssum;
  int i = blockIdx.x * blockDim.x + threadIdx.x;
  if (i < n) out[i] = __expf(a[i]) * inv;
}

// ---------------- per-layer driver ----------------
template<int DIN, int DOUT, int H, bool HAS_RES>
static void run_layer(const float* xin, const float* W, const float* as_,
                      const float* ad_, const float* bias, const float* Aw,
                      const float* Ab, const float* g, const float* be,
                      const int* row_ptr, const unsigned short* col,
                      const unsigned short* dste, const int* orig,
                      unsigned short* hw16, float* res, float* als, float* ald,
                      float* inv_s, float* amean, float* scal,
                      float* hout, float* eout, hipStream_t stream)
{
  constexpr int NPW = 8;
  constexpr int NPB = 4 * NPW * (64 / DOUT);
  constexpr int G = DOUT / 2;
  hipMemsetAsync(scal, 0, sizeof(float), stream);
  gemm_al_kernel<DIN, DOUT, H, HAS_RES, NPW><<<NN / NPB, 256, 0, stream>>>(
      xin, W, as_, ad_, Aw, Ab, hw16, res, als, ald);
  gat_gather_kernel<DOUT, H, HAS_RES><<<(NN * G) / 256, 256, 0, stream>>>(
      row_ptr, col, als, ald, (const unsigned*)hw16, bias, g, be, res, hout, inv_s);
  amean_csr_kernel<H><<<(ET + 255) / 256, 256, 0, stream>>>(
      col, dste, orig, als, ald, inv_s, amean, scal);
  write_softmax_kernel<<<EE / 256, 256, 0, stream>>>(amean, EE, scal, eout);
}

extern "C" void kernel_launch(void* const* d_in, const int* in_sizes, int n_in,
                              void* d_out, int out_size, void* d_ws, size_t ws_size,
                              hipStream_t stream)
{
  const float* x   = (const float*)d_in[0];
  const int*   ei  = (const int*)d_in[1];
  const float* W1  = (const float*)d_in[3];
  const float* as1 = (const float*)d_in[4];
  const float* ad1 = (const float*)d_in[5];
  const float* b1  = (const float*)d_in[6];
  const float* W2  = (const float*)d_in[7];
  const float* as2 = (const float*)d_in[8];
  const float* ad2 = (const float*)d_in[9];
  const float* b2  = (const float*)d_in[10];
  const float* W3  = (const float*)d_in[11];
  const float* as3 = (const float*)d_in[12];
  const float* ad3 = (const float*)d_in[13];
  const float* b3  = (const float*)d_in[14];
  const float* A1w = (const float*)d_in[15];
  const float* A1b = (const float*)d_in[16];
  const float* A2w = (const float*)d_in[17];
  const float* A2b = (const float*)d_in[18];
  const float* g1  = (const float*)d_in[19];
  const float* be1 = (const float*)d_in[20];
  const float* g2  = (const float*)d_in[21];
  const float* be2 = (const float*)d_in[22];
  const float* g3  = (const float*)d_in[23];
  const float* be3 = (const float*)d_in[24];

  float* ws = (float*)d_ws;
  size_t off = 0;
  float* h1       = ws + off; off += (size_t)NN * 64;
  float* h2       = ws + off; off += (size_t)NN * 32;
  unsigned short* hw16 = (unsigned short*)(ws + off); off += (size_t)NN * 32;
  float* res      = ws + off; off += (size_t)NN * 64;
  float* als      = ws + off; off += (size_t)NN * 16;
  float* ald      = ws + off; off += (size_t)NN * 16;
  float* inv_s    = ws + off; off += (size_t)NN * 16;
  float* amean    = ws + off; off += (size_t)EE;
  float* scal     = ws + off; off += 16;
  int* row_ptr    = (int*)(ws + off); off += NN + 4;
  unsigned short* col  = (unsigned short*)(ws + off); off += ET / 2;
  unsigned short* dste = (unsigned short*)(ws + off); off += ET / 2;
  int* orig       = (int*)(ws + off); off += ET;
  int* gcnt       = (int*)(ws + off); off += 256;
  unsigned* staging  = (unsigned*)(ws + off); off += (size_t)256 * CAPB;
  unsigned* staging2 = (unsigned*)(ws + off); off += (size_t)256 * CAPB;

  float* outh3 = (float*)d_out;
  float* oute1 = outh3 + (size_t)NN * 16;
  float* oute2 = oute1 + EE;
  float* oute3 = oute2 + EE;

  // ---- CSR build via coarse-bucket sort (graph-capture safe) ----
  hipMemsetAsync(gcnt, 0, 256 * sizeof(int), stream);
  bucket_pass1<<<P1B, 256, 0, stream>>>(ei, staging, staging2, gcnt);
  bucket_pass2<<<256, 256, 0, stream>>>(staging, staging2, gcnt, row_ptr, col, dste, orig);

  run_layer<84, 64, 16, true>(x, W1, as1, ad1, b1, A1w, A1b, g1, be1,
                              row_ptr, col, dste, orig, hw16, res, als, ald,
                              inv_s, amean, scal, h1, oute1, stream);
  run_layer<64, 32, 8, true>(h1, W2, as2, ad2, b2, A2w, A2b, g2, be2,
                             row_ptr, col, dste, orig, hw16, res, als, ald,
                             inv_s, amean, scal, h2, oute2, stream);
  run_layer<32, 16, 4, false>(h2, W3, as3, ad3, b3, nullptr, nullptr, g3, be3,
                              row_ptr, col, dste, orig, hw16, res, als, ald,
                              inv_s, amean, scal, outh3, oute3, stream);
}

// Round 8
// 359.535 us; speedup vs baseline: 1.0763x; 1.0763x over previous
//
#include <hip/hip_runtime.h>
#include <math.h>

#define NN 65536
#define EE 1048576
#define ET (EE + NN)

#define CAPB 5120          // staging capacity per coarse bucket (mean 4352, +11.6 sigma)
#define EPB 4096           // edges per pass-1 block
#define P1B (ET / EPB)     // 272 blocks

__device__ __forceinline__ float bflo(unsigned u) { return __uint_as_float(u << 16); }
__device__ __forceinline__ float bfhi(unsigned u) { return __uint_as_float(u & 0xffff0000u); }
__device__ __forceinline__ float lrelu(float x) { return x > 0.f ? x : 0.2f * x; }
__device__ __forceinline__ unsigned short f2bf(float f) {
  unsigned u = __float_as_uint(f);
  return (unsigned short)((u + 0x7fffu + ((u >> 16) & 1u)) >> 16);
}

// ---------------- CSR build via 2-pass coarse-bucket counting sort ----------------
__global__ __launch_bounds__(256) void bucket_pass1(const int* __restrict__ ei,
                                                    unsigned* __restrict__ staging,
                                                    int* __restrict__ gcnt) {
  __shared__ int hist[256];
  __shared__ int lbase[256];
  int t = threadIdx.x;
  hist[t] = 0;
  __syncthreads();
  int base = blockIdx.x * EPB;
  unsigned pk[16];
  int bk[16];
  #pragma unroll
  for (int j = 0; j < 16; ++j) {
    int e = base + j * 256 + t;
    int s, d;
    if (e < EE) { s = ei[e]; d = ei[EE + e]; } else { s = d = e - EE; }
    pk[j] = ((unsigned)s << 8) | (unsigned)(d & 255);
    bk[j] = d >> 8;
    atomicAdd(&hist[bk[j]], 1);
  }
  __syncthreads();
  lbase[t] = atomicAdd(&gcnt[t], hist[t]);   // reserve contiguous chunk per bucket
  __syncthreads();
  #pragma unroll
  for (int j = 0; j < 16; ++j) {
    int pos = atomicAdd(&lbase[bk[j]], 1);
    staging[(size_t)bk[j] * CAPB + pos] = pk[j];
  }
}

__global__ __launch_bounds__(256) void bucket_pass2(const unsigned* __restrict__ staging,
                                                    const int* __restrict__ gcnt,
                                                    int* __restrict__ row_ptr,
                                                    unsigned short* __restrict__ col) {
  __shared__ int pref[256];
  __shared__ int hist[256];
  __shared__ int loc[256];
  __shared__ int cnt2[256];
  __shared__ unsigned lin[CAPB];
  __shared__ unsigned short lout[CAPB];
  int t = threadIdx.x, b = blockIdx.x;

  pref[t] = gcnt[t];
  hist[t] = 0;
  __syncthreads();
  for (int off = 1; off < 256; off <<= 1) {      // inclusive scan of bucket counts
    int v = (t >= off) ? pref[t - off] : 0;
    __syncthreads();
    pref[t] += v;
    __syncthreads();
  }
  int rowbase = (b > 0) ? pref[b - 1] : 0;
  int nb = gcnt[b];

  for (int i = t; i < nb; i += 256) {
    unsigned v = staging[(size_t)b * CAPB + i];
    lin[i] = v;
    atomicAdd(&hist[v & 255], 1);
  }
  __syncthreads();
  loc[t] = hist[t];
  __syncthreads();
  for (int off = 1; off < 256; off <<= 1) {      // inclusive scan of local hist
    int v = (t >= off) ? loc[t - off] : 0;
    __syncthreads();
    loc[t] += v;
    __syncthreads();
  }
  int excl = loc[t] - hist[t];
  row_ptr[b * 256 + t] = rowbase + excl;
  cnt2[t] = excl;
  if (b == 255 && t == 255) row_ptr[NN] = rowbase + nb;
  __syncthreads();
  for (int i = t; i < nb; i += 256) {
    unsigned v = lin[i];
    int r = atomicAdd(&cnt2[v & 255], 1);
    lout[r] = (unsigned short)(v >> 8);
  }
  __syncthreads();
  for (int i = t; i < nb; i += 256) col[rowbase + i] = lout[i];  // coalesced
}

// -------- dense: h = x@W, al_s/al_d, residual; register-blocked over nodes --------
// hW as bf16 for gather; als/ald f32 for gather + bf16 into combo tables for amean.
template<int DIN, int DOUT, int H, bool HAS_RES, int NPW, int CS_OFF, int ALD_OFF>
__global__ __launch_bounds__(256) void gemm_al_kernel(
    const float* __restrict__ xin, const float* __restrict__ W,
    const float* __restrict__ asrc, const float* __restrict__ adst,
    const float* __restrict__ Aw, const float* __restrict__ Ab,
    unsigned short* __restrict__ hw16, float* __restrict__ res,
    float* __restrict__ als, float* __restrict__ ald,
    unsigned short* __restrict__ cs, unsigned short* __restrict__ cd)
{
  constexpr int GPW = 64 / DOUT;
  constexpr int NPB = 4 * NPW * GPW;   // nodes per block (4 waves)
  constexpr int DINP = DIN + 4;        // padded LDS stride
  __shared__ float xs[NPB][DINP];

  int wave = threadIdx.x >> 6;
  int lane = threadIdx.x & 63;
  int l = lane % DOUT;
  int sub = lane / DOUT;
  int block_base = blockIdx.x * NPB;

  {
    constexpr int NV = NPB * DIN / 4;
    const float4* xin4 = (const float4*)(xin + (size_t)block_base * DIN);
    for (int i = threadIdx.x; i < NV; i += 256) {
      float4 v = xin4[i];
      int flat = i * 4;
      int nd = flat / DIN, k = flat % DIN;
      *(float4*)&xs[nd][k] = v;
    }
  }
  __syncthreads();

  int nl = wave * (NPW * GPW) + sub * NPW;
  float acc[NPW], racc[NPW];
  #pragma unroll
  for (int n = 0; n < NPW; ++n) { acc[n] = 0.f; racc[n] = 0.f; }

  for (int k = 0; k < DIN; k += 4) {
    float w0 = W[(k + 0) * DOUT + l];
    float w1 = W[(k + 1) * DOUT + l];
    float w2 = W[(k + 2) * DOUT + l];
    float w3 = W[(k + 3) * DOUT + l];
    float a0 = 0.f, a1 = 0.f, a2 = 0.f, a3 = 0.f;
    if (HAS_RES) {
      a0 = Aw[(k + 0) * DOUT + l];
      a1 = Aw[(k + 1) * DOUT + l];
      a2 = Aw[(k + 2) * DOUT + l];
      a3 = Aw[(k + 3) * DOUT + l];
    }
    #pragma unroll
    for (int n = 0; n < NPW; ++n) {
      float4 xv = *(const float4*)&xs[nl + n][k];
      acc[n] = fmaf(xv.x, w0, fmaf(xv.y, w1, fmaf(xv.z, w2, fmaf(xv.w, w3, acc[n]))));
      if (HAS_RES)
        racc[n] = fmaf(xv.x, a0, fmaf(xv.y, a1, fmaf(xv.z, a2, fmaf(xv.w, a3, racc[n]))));
    }
  }

  int head = l >> 2, c = l & 3;
  float sa = asrc[l];
  float da = adst[l];
  #pragma unroll
  for (int n = 0; n < NPW; ++n) {
    size_t node = (size_t)(block_base + nl + n);
    float hh = acc[n];
    hw16[node * DOUT + l] = f2bf(hh);
    if (HAS_RES) res[node * DOUT + l] = racc[n] + Ab[l];
    float ps = hh * sa, pd = hh * da;
    ps += __shfl_xor(ps, 1); ps += __shfl_xor(ps, 2);
    pd += __shfl_xor(pd, 1); pd += __shfl_xor(pd, 2);
    if (c == 0) {
      als[node * H + head] = ps;
      ald[node * H + head] = pd;
      cs[node * 32 + CS_OFF + head] = f2bf(ps);
      cd[node * 64 + ALD_OFF + head] = f2bf(pd);
    }
  }
}

// ---------------- fused gather: bf16x2 channels, DOUT/2 lanes per node ----------------
template<int DOUT, int H, bool HAS_RES, int INV_OFF>
__global__ __launch_bounds__(256) void gat_gather_kernel(
    const int* __restrict__ row_ptr, const unsigned short* __restrict__ col,
    const float* __restrict__ als, const float* __restrict__ ald,
    const unsigned* __restrict__ hw2,   // bf16x2: channels (2l, 2l+1)
    const float* __restrict__ bias, const float* __restrict__ g,
    const float* __restrict__ be, const float* __restrict__ res,
    float* __restrict__ out, unsigned short* __restrict__ cd)
{
  constexpr int G = DOUT / 2;          // lanes per node
  int tid = blockIdx.x * 256 + threadIdx.x;
  int node = tid / G;
  int l = threadIdx.x % G;             // group lane: channels 2l, 2l+1
  int h = l >> 1;                      // head (2 lanes per head)

  int r0 = row_ptr[node], r1 = row_ptr[node + 1];
  float ald_h = ald[node * H + h];

  float acc0 = 0.f, acc1 = 0.f, ss = 0.f;
  int e = r0;
  for (; e + 3 < r1; e += 4) {
    int s0 = col[e], s1 = col[e + 1], s2 = col[e + 2], s3 = col[e + 3];
    float av0 = als[s0 * H + h];
    float av1 = als[s1 * H + h];
    float av2 = als[s2 * H + h];
    float av3 = als[s3 * H + h];
    unsigned p0 = hw2[s0 * G + l];
    unsigned p1 = hw2[s1 * G + l];
    unsigned p2 = hw2[s2 * G + l];
    unsigned p3 = hw2[s3 * G + l];
    float lg0 = lrelu(av0 + ald_h);
    float lg1 = lrelu(av1 + ald_h);
    float lg2 = lrelu(av2 + ald_h);
    float lg3 = lrelu(av3 + ald_h);
    float e0 = __expf(lg0), e1 = __expf(lg1), e2 = __expf(lg2), e3 = __expf(lg3);
    ss += (e0 + e1) + (e2 + e3);
    acc0 += e0 * bflo(p0) + e1 * bflo(p1) + e2 * bflo(p2) + e3 * bflo(p3);
    acc1 += e0 * bfhi(p0) + e1 * bfhi(p1) + e2 * bfhi(p2) + e3 * bfhi(p3);
  }
  for (; e < r1; ++e) {
    int s0 = col[e];
    float av0 = als[s0 * H + h];
    unsigned p0 = hw2[s0 * G + l];
    float lg0 = lrelu(av0 + ald_h);
    float e0 = __expf(lg0);
    ss += e0;
    acc0 += e0 * bflo(p0);
    acc1 += e0 * bfhi(p0);
  }

  float inv = 1.f / ss;                // identical across the 2 lanes of a head
  if ((l & 1) == 0) cd[node * 64 + INV_OFF + h] = f2bf(inv);

  // epilogue: normalize -> bias -> elu -> layernorm -> (+res), 2 channels/lane
  float2 bb = ((const float2*)bias)[l];
  float v0 = acc0 * inv + bb.x;
  float v1 = acc1 * inv + bb.y;
  v0 = v0 > 0.f ? v0 : expm1f(v0);
  v1 = v1 > 0.f ? v1 : expm1f(v1);
  float sum = v0 + v1;
  #pragma unroll
  for (int o = G / 2; o; o >>= 1) sum += __shfl_xor(sum, o);
  float mu = sum * (1.f / DOUT);
  float d0 = v0 - mu, d1 = v1 - mu;
  float vs = d0 * d0 + d1 * d1;
  #pragma unroll
  for (int o = G / 2; o; o >>= 1) vs += __shfl_xor(vs, o);
  float rstd = rsqrtf(vs * (1.f / DOUT) + 1e-5f);
  float2 gg = ((const float2*)g)[l];
  float2 ee = ((const float2*)be)[l];
  float y0 = d0 * rstd * gg.x + ee.x;
  float y1 = d1 * rstd * gg.y + ee.y;
  if (HAS_RES) {
    float2 rr = ((const float2*)res)[node * G + l];
    y0 += rr.x; y1 += rr.y;
  }
  ((float2*)out)[node * G + l] = make_float2(y0, y1);
}

// ------- all-layer per-edge head-mean alpha, original edge order (coalesced) -------
// combo_s row (64B): als1[16] als2[8] als3[4] pad[4]   (bf16)
// combo_d row (128B): ald1[16] inv1[16] ald2[8] inv2[8] ald3[4] inv3[4] pad[8]
__global__ __launch_bounds__(256) void amean_all_kernel(
    const int* __restrict__ ei, const unsigned* __restrict__ cs,
    const unsigned* __restrict__ cd, float* __restrict__ am1,
    float* __restrict__ am2, float* __restrict__ am3, float* __restrict__ ssum)
{
  __shared__ float red[3][4];
  int e = blockIdx.x * 256 + threadIdx.x;
  float ex1 = 0.f, ex2 = 0.f, ex3 = 0.f;
  {
    int s = ei[e], d = ei[EE + e];
    const unsigned* rs = cs + (size_t)s * 16;
    const unsigned* rd = cd + (size_t)d * 32;
    uint4 s0 = *(const uint4*)(rs);
    uint4 s1 = *(const uint4*)(rs + 4);
    uint4 s2 = *(const uint4*)(rs + 8);
    uint2 s3 = *(const uint2*)(rs + 12);
    uint4 a0 = *(const uint4*)(rd);
    uint4 a1 = *(const uint4*)(rd + 4);
    uint4 i0 = *(const uint4*)(rd + 8);
    uint4 i1 = *(const uint4*)(rd + 12);
    uint4 a2 = *(const uint4*)(rd + 16);
    uint4 i2 = *(const uint4*)(rd + 20);
    uint2 a3 = *(const uint2*)(rd + 24);
    uint2 i3 = *(const uint2*)(rd + 26);
    // layer 1 (H=16)
    {
      unsigned S[8] = {s0.x, s0.y, s0.z, s0.w, s1.x, s1.y, s1.z, s1.w};
      unsigned A[8] = {a0.x, a0.y, a0.z, a0.w, a1.x, a1.y, a1.z, a1.w};
      unsigned I[8] = {i0.x, i0.y, i0.z, i0.w, i1.x, i1.y, i1.z, i1.w};
      float t = 0.f;
      #pragma unroll
      for (int q = 0; q < 8; ++q) {
        float l0 = lrelu(bflo(S[q]) + bflo(A[q]));
        float l1 = lrelu(bfhi(S[q]) + bfhi(A[q]));
        t += __expf(l0) * bflo(I[q]) + __expf(l1) * bfhi(I[q]);
      }
      t *= (1.f / 16.f);
      am1[e] = t;
      ex1 = __expf(t);
    }
    // layer 2 (H=8)
    {
      unsigned S[4] = {s2.x, s2.y, s2.z, s2.w};
      unsigned A[4] = {a2.x, a2.y, a2.z, a2.w};
      unsigned I[4] = {i2.x, i2.y, i2.z, i2.w};
      float t = 0.f;
      #pragma unroll
      for (int q = 0; q < 4; ++q) {
        float l0 = lrelu(bflo(S[q]) + bflo(A[q]));
        float l1 = lrelu(bfhi(S[q]) + bfhi(A[q]));
        t += __expf(l0) * bflo(I[q]) + __expf(l1) * bfhi(I[q]);
      }
      t *= (1.f / 8.f);
      am2[e] = t;
      ex2 = __expf(t);
    }
    // layer 3 (H=4)
    {
      unsigned S[2] = {s3.x, s3.y};
      unsigned A[2] = {a3.x, a3.y};
      unsigned I[2] = {i3.x, i3.y};
      float t = 0.f;
      #pragma unroll
      for (int q = 0; q < 2; ++q) {
        float l0 = lrelu(bflo(S[q]) + bflo(A[q]));
        float l1 = lrelu(bfhi(S[q]) + bfhi(A[q]));
        t += __expf(l0) * bflo(I[q]) + __expf(l1) * bfhi(I[q]);
      }
      t *= (1.f / 4.f);
      am3[e] = t;
      ex3 = __expf(t);
    }
  }
  #pragma unroll
  for (int o = 32; o; o >>= 1) {
    ex1 += __shfl_xor(ex1, o);
    ex2 += __shfl_xor(ex2, o);
    ex3 += __shfl_xor(ex3, o);
  }
  int w = threadIdx.x >> 6;
  if ((threadIdx.x & 63) == 0) { red[0][w] = ex1; red[1][w] = ex2; red[2][w] = ex3; }
  __syncthreads();
  if (threadIdx.x == 0) {
    atomicAdd(&ssum[0], (red[0][0] + red[0][1]) + (red[0][2] + red[0][3]));
    atomicAdd(&ssum[1], (red[1][0] + red[1][1]) + (red[1][2] + red[1][3]));
    atomicAdd(&ssum[2], (red[2][0] + red[2][1]) + (red[2][2] + red[2][3]));
  }
}

__global__ __launch_bounds__(256) void write_softmax_kernel(
    const float* __restrict__ a, int n, const float* __restrict__ ssum,
    float* __restrict__ out)
{
  float inv = 1.f / *ssum;
  int i = blockIdx.x * blockDim.x + threadIdx.x;
  if (i < n) out[i] = __expf(a[i]) * inv;
}

// ---------------- per-layer driver ----------------
template<int DIN, int DOUT, int H, bool HAS_RES, int CS_OFF, int ALD_OFF, int INV_OFF>
static void run_layer(const float* xin, const float* W, const float* as_,
                      const float* ad_, const float* bias, const float* Aw,
                      const float* Ab, const float* g, const float* be,
                      const int* row_ptr, const unsigned short* col,
                      unsigned short* hw16, float* res, float* als, float* ald,
                      unsigned short* cs, unsigned short* cd,
                      float* hout, hipStream_t stream)
{
  constexpr int NPW = 8;
  constexpr int NPB = 4 * NPW * (64 / DOUT);
  constexpr int G = DOUT / 2;
  gemm_al_kernel<DIN, DOUT, H, HAS_RES, NPW, CS_OFF, ALD_OFF><<<NN / NPB, 256, 0, stream>>>(
      xin, W, as_, ad_, Aw, Ab, hw16, res, als, ald, cs, cd);
  gat_gather_kernel<DOUT, H, HAS_RES, INV_OFF><<<(NN * G) / 256, 256, 0, stream>>>(
      row_ptr, col, als, ald, (const unsigned*)hw16, bias, g, be, res, hout, cd);
}

extern "C" void kernel_launch(void* const* d_in, const int* in_sizes, int n_in,
                              void* d_out, int out_size, void* d_ws, size_t ws_size,
                              hipStream_t stream)
{
  const float* x   = (const float*)d_in[0];
  const int*   ei  = (const int*)d_in[1];
  const float* W1  = (const float*)d_in[3];
  const float* as1 = (const float*)d_in[4];
  const float* ad1 = (const float*)d_in[5];
  const float* b1  = (const float*)d_in[6];
  const float* W2  = (const float*)d_in[7];
  const float* as2 = (const float*)d_in[8];
  const float* ad2 = (const float*)d_in[9];
  const float* b2  = (const float*)d_in[10];
  const float* W3  = (const float*)d_in[11];
  const float* as3 = (const float*)d_in[12];
  const float* ad3 = (const float*)d_in[13];
  const float* b3  = (const float*)d_in[14];
  const float* A1w = (const float*)d_in[15];
  const float* A1b = (const float*)d_in[16];
  const float* A2w = (const float*)d_in[17];
  const float* A2b = (const float*)d_in[18];
  const float* g1  = (const float*)d_in[19];
  const float* be1 = (const float*)d_in[20];
  const float* g2  = (const float*)d_in[21];
  const float* be2 = (const float*)d_in[22];
  const float* g3  = (const float*)d_in[23];
  const float* be3 = (const float*)d_in[24];

  float* ws = (float*)d_ws;
  size_t off = 0;
  float* h1       = ws + off; off += (size_t)NN * 64;
  float* h2       = ws + off; off += (size_t)NN * 32;
  unsigned short* hw16 = (unsigned short*)(ws + off); off += (size_t)NN * 32;
  float* res      = ws + off; off += (size_t)NN * 64;
  float* als      = ws + off; off += (size_t)NN * 16;
  float* ald      = ws + off; off += (size_t)NN * 16;
  unsigned short* combo_s = (unsigned short*)(ws + off); off += (size_t)NN * 16;  // 32 bf16/node
  unsigned short* combo_d = (unsigned short*)(ws + off); off += (size_t)NN * 32;  // 64 bf16/node
  float* am1      = ws + off; off += (size_t)EE;
  float* am2      = ws + off; off += (size_t)EE;
  float* am3      = ws + off; off += (size_t)EE;
  float* scal     = ws + off; off += 16;
  int* row_ptr    = (int*)(ws + off); off += NN + 4;
  unsigned short* col = (unsigned short*)(ws + off); off += ET / 2 + 4;
  int* gcnt       = (int*)(ws + off); off += 256;
  unsigned* staging = (unsigned*)(ws + off); off += (size_t)256 * CAPB;

  float* outh3 = (float*)d_out;
  float* oute1 = outh3 + (size_t)NN * 16;
  float* oute2 = oute1 + EE;
  float* oute3 = oute2 + EE;

  // ---- CSR build via coarse-bucket sort (graph-capture safe) ----
  hipMemsetAsync(gcnt, 0, 256 * sizeof(int), stream);
  hipMemsetAsync(scal, 0, 16, stream);
  bucket_pass1<<<P1B, 256, 0, stream>>>(ei, staging, gcnt);
  bucket_pass2<<<256, 256, 0, stream>>>(staging, gcnt, row_ptr, col);

  // combo slot offsets (bf16 units): cs: L1@0 L2@16 L3@24; cd: ald L1@0 L2@32 L3@48,
  //                                  inv L1@16 L2@40 L3@52
  run_layer<84, 64, 16, true, 0, 0, 16>(x, W1, as1, ad1, b1, A1w, A1b, g1, be1,
                                        row_ptr, col, hw16, res, als, ald,
                                        combo_s, combo_d, h1, stream);
  run_layer<64, 32, 8, true, 16, 32, 40>(h1, W2, as2, ad2, b2, A2w, A2b, g2, be2,
                                         row_ptr, col, hw16, res, als, ald,
                                         combo_s, combo_d, h2, stream);
  run_layer<32, 16, 4, false, 24, 48, 52>(h2, W3, as3, ad3, b3, nullptr, nullptr, g3, be3,
                                          row_ptr, col, hw16, res, als, ald,
                                          combo_s, combo_d, outh3, stream);

  amean_all_kernel<<<EE / 256, 256, 0, stream>>>(
      ei, (const unsigned*)combo_s, (const unsigned*)combo_d, am1, am2, am3, scal);
  write_softmax_kernel<<<EE / 256, 256, 0, stream>>>(am1, EE, scal + 0, oute1);
  write_softmax_kernel<<<EE / 256, 256, 0, stream>>>(am2, EE, scal + 1, oute2);
  write_softmax_kernel<<<EE / 256, 256, 0, stream>>>(am3, EE, scal + 2, oute3);
}